// Round 12
// baseline (17545.230 us; speedup 1.0000x reference)
//
#include <hip/hip_runtime.h>

// DA-RNN persistent kernel, round 13 RESUBMIT (prior bench died on container
// acquire, not kernel): two 512-thread co-resident blocks/CU.
// R10 post-mortem: co-residency raised occupancy 48->91 but the allocator
// pinned TB=1024 at VGPR=32 -> spill -> 17.2 ms. The VGPR heuristic starves
// 1024-thread blocks at high occupancy targets (7 rounds of evidence).
// This round: TB=512, BB=2, 80 KB LDS -> 2 blocks/CU = SAME 16 waves/CU as
// R9 but in TWO independent barrier domains (block A computes while B drains).
// launch_bounds(512,4) = exactly 16 waves/CU -> VGPR cap 128, working set ~45,
// no starvation mode. Streams identical to R9: k<128 half of uexT/udmT in
// 64 KB LDS, k>=128 from HBM (nt), ~6 GB total. Math = R9/R10 (passed).
// Phase remap for TB=512: k-half split in (b)/(a'); gate phases do rows
// o and o+512; score threads (b,kh,j) do 128 k each.

#define B_   1024
#define T_   128     // T_ENCO
#define NI_  128     // N_INP
#define H_   256     // N_HID
#define H4_  1024    // 4*N_HID
#define TD_  24      // T_DECO
#define DS_  30      // decoder steps
#define BB   2       // batch rows per workgroup
#define TB   512     // threads per block
#define LDS_BYTES 81920u   // 16 KB wk + 64 KB u1; 2 blocks/CU = 160 KB

typedef _Float16 hf_t;
typedef _Float16 half8  __attribute__((ext_vector_type(8)));
typedef _Float16 half2v __attribute__((ext_vector_type(2)));

__device__ __forceinline__ float sigm(float x) {
    return __builtin_amdgcn_rcpf(1.0f + __expf(-x));
}
__device__ __forceinline__ float tanh_f(float x) {
    float e = __expf(2.0f * x);
    return 1.0f - 2.0f * __builtin_amdgcn_rcpf(e + 1.0f);
}
__device__ __forceinline__ float fdot2f(half2v a, half2v b, float c) {
#if __has_builtin(__builtin_amdgcn_fdot2)
    return __builtin_amdgcn_fdot2(a, b, c, false);
#else
    return fmaf((float)a.x, (float)b.x, fmaf((float)a.y, (float)b.y, c));
#endif
}
__device__ __forceinline__ float dot8h(half8 w, half8 x, float acc) {
    acc = fdot2f(__builtin_shufflevector(w, w, 0, 1), __builtin_shufflevector(x, x, 0, 1), acc);
    acc = fdot2f(__builtin_shufflevector(w, w, 2, 3), __builtin_shufflevector(x, x, 2, 3), acc);
    acc = fdot2f(__builtin_shufflevector(w, w, 4, 5), __builtin_shufflevector(x, x, 4, 5), acc);
    acc = fdot2f(__builtin_shufflevector(w, w, 6, 7), __builtin_shufflevector(x, x, 6, 7), acc);
    return acc;
}
__device__ __forceinline__ hf_t nt_load_h(const hf_t* p) {
#if __has_builtin(__builtin_nontemporal_load)
    return __builtin_nontemporal_load(p);
#else
    return *p;
#endif
}
__device__ __forceinline__ void nt_store_h(hf_t v, hf_t* p) {
#if __has_builtin(__builtin_nontemporal_store)
    __builtin_nontemporal_store(v, p);
#else
    *p = v;
#endif
}

// ---- f16 weight layout inside d_ws (offsets in halves) ----
#define W_WE    0u
#define W_UE2   131072u
#define W_EWIH  163840u
#define W_EWHH  294912u
#define W_MWIH  557056u
#define W_MWHH  819200u
#define W_DWIH  1081344u
#define W_DWHH  1343488u
#define W_WD    1605632u
#define W_UD    1736704u
#define SCR_A   2097152u       // upper halves: uexT k>=128 -> udmT o>=128 [b][0..127][j]
#define SCR_B   35651584u      // midb [b][t][k]

__global__ void convw_kernel(const float* __restrict__ sWE, const float* __restrict__ sUE2,
                             const float* __restrict__ sEI, const float* __restrict__ sEH,
                             const float* __restrict__ sMI, const float* __restrict__ sMH,
                             const float* __restrict__ sDI, const float* __restrict__ sDH,
                             const float* __restrict__ sWD, const float* __restrict__ sUD,
                             hf_t* __restrict__ dst) {
    const int gtid = blockIdx.x * blockDim.x + threadIdx.x;
    const int gs   = gridDim.x * blockDim.x;
    for (int n = gtid; n < 131072; n += gs) {       // WE'
        int e = n & 7, q = n >> 3, k = q & 255, c = q >> 8, kq = c >> 4, i = c & 15;
        dst[W_WE + n] = (hf_t)sWE[k * 512 + kq * 128 + i * 8 + e];
    }
    for (int n = gtid; n < 32768; n += gs) {        // UE2'
        int e = n & 7, q = n >> 3, k = q & 255, c = q >> 8, kq = c >> 2, i = c & 3;
        dst[W_UE2 + n] = (hf_t)sUE2[k * 128 + kq * 32 + i * 8 + e];
    }
    for (int n = gtid; n < 131072; n += gs) {       // EWIH' (K=128)
        int e = n & 7, q = n >> 3, o = q & 1023, i = q >> 10;
        dst[W_EWIH + n] = (hf_t)sEI[o * 128 + i * 8 + e];
    }
    for (int n = gtid; n < 262144; n += gs) {       // K=256 gates
        int e = n & 7, q = n >> 3, o = q & 1023, i = q >> 10;
        int s = o * 256 + i * 8 + e;
        dst[W_EWHH + n] = (hf_t)sEH[s];
        dst[W_MWIH + n] = (hf_t)sMI[s];
        dst[W_MWHH + n] = (hf_t)sMH[s];
        dst[W_DWIH + n] = (hf_t)sDI[s];
        dst[W_DWHH + n] = (hf_t)sDH[s];
    }
    for (int n = gtid; n < 131072; n += gs) {       // WD'
        int e = n & 7, q = n >> 3, k = q & 255, c = q >> 8, kq = c >> 4, i = c & 15;
        dst[W_WD + n] = (hf_t)sWD[k * 512 + kq * 128 + i * 8 + e];
    }
    for (int n = gtid; n < 65536; n += gs)          // UD plain
        dst[W_UD + n] = (hf_t)sUD[n];
}

// ---- wk offsets (floats, wk = sm[0..4096) = 16 KB) ----
#define O_HC    0        // hf [2][512]                       512f
#define O_HM    512      // hf [2][256] (decoder: dinh)       256f
#define O_XRAW  768      // f32 [2][128]                      256f
#define O_XHG   1024     // hf [2][128]  xh then xg           128f
#define O_HCXI  1152     // f32 [2][256]                      512f
#define O_RED   1664     // f32 [16] output-reduce partials
#define O_GBUF  2048     // f32 [2048] gates / partials / scores / sbuf
// phase-0 X staging reuses wk[0..4096) as f32[128][32] quarters

__global__ __launch_bounds__(TB, 4) void dsrnn_kernel(
    const float* __restrict__ inp,
    const float* __restrict__ UeW,  const float* __restrict__ Ueb,
    const float* __restrict__ Ue2b,
    const float* __restrict__ Web,
    const float* __restrict__ VeW,  const float* __restrict__ Veb,
    const float* __restrict__ Udb,
    const float* __restrict__ Wdb,
    const float* __restrict__ VdW,  const float* __restrict__ Vdb,
    const float* __restrict__ ebih, const float* __restrict__ ebhh,
    const float* __restrict__ mbih, const float* __restrict__ mbhh,
    const float* __restrict__ dbih, const float* __restrict__ dbhh,
    const float* __restrict__ rW,   const float* __restrict__ rb,
    const hf_t* __restrict__ wb,
    hf_t* __restrict__ scrA,
    hf_t* __restrict__ scrB,
    float* __restrict__ out)
{
    extern __shared__ float sm[];
    float* wk = sm;                       // 4096 floats = 16 KB
    hf_t*  u1 = (hf_t*)(sm + 4096);       // 32768 halves = 64 KB

    const int tid = threadIdx.x;
    const int b0  = blockIdx.x * BB;

    hf_t*  hc   = (hf_t*)(wk + O_HC);
    hf_t*  hm   = (hf_t*)(wk + O_HM);
    float* xraw = wk + O_XRAW;
    hf_t*  xhg  = (hf_t*)(wk + O_XHG);
    float* hcxi = wk + O_HCXI;
    float* red  = wk + O_RED;
    float* gbuf = wk + O_GBUF;
    hf_t*  dinh = (hf_t*)(wk + O_HM);     // decoder alias of HM

    // ---------- Phase 0: uexT; k<128 -> LDS u1, k>=128 -> scrA (nt) ----------
    // X staged in f32 [128][32] j-quarters (16 KB), exact f32 accumulate.
    // 16 k-groups x 32 j-lanes; each group does 16 k.
    {
        const int jj = tid & 31;        // j within quarter
        const int kg = tid >> 5;        // 16 groups x 16 k
        for (int b = 0; b < BB; ++b) {
            const float* Xg = inp + (size_t)(b0 + b) * T_ * NI_;
            for (int jq = 0; jq < 4; ++jq) {
                __syncthreads();
                for (int i = tid; i < 128 * 32; i += TB) {
                    int t = i >> 5, j2 = i & 31;
                    wk[i] = Xg[t * NI_ + jq * 32 + j2];
                }
                __syncthreads();
                const int j = jq * 32 + jj;
                for (int k = kg * 16; k < kg * 16 + 16; ++k) {
                    const float* wrow = UeW + (size_t)k * T_;
                    float acc = Ueb[k];
#pragma unroll 4
                    for (int t = 0; t < T_; ++t) acc = fmaf(wrow[t], wk[t * 32 + jj], acc);
                    if (k < 128)
                        u1[((size_t)(b * 128) + k) * 128 + j] = (hf_t)acc;
                    else
                        nt_store_h((hf_t)acc,
                                   scrA + (((size_t)(b0 + b) * 128) + (k - 128)) * 128 + j);
                }
            }
        }
    }
    __syncthreads();
    for (int i = tid; i < 768; i += TB) wk[i] = 0.0f;    // zero hc + hm
    __syncthreads();

    float c_enc = 0.0f, c_mid = 0.0f;   // f32 c-states in regs, (b,k)=tid

    // ---------- Fused encoder + mid loop ----------
    for (int t = 0; t < T_; ++t) {
        // (a) load x_t
        if (tid < 256) {
            const int b = tid >> 7, j = tid & 127;
            float v = inp[((size_t)(b0 + b) * T_ + t) * NI_ + j];
            xraw[b * NI_ + j] = v;
            xhg[b * NI_ + j]  = (hf_t)v;
        }
        __syncthreads();

        // (b) We.[h;c] + Ue2.x partials, k-HALF split (kh = 0,1)
        {
            const int k = tid & 255, kh = tid >> 8;
            const half8* wWE = (const half8*)(wb + W_WE)  + (size_t)(kh * 32) * 256 + k;
            const half8* wU2 = (const half8*)(wb + W_UE2) + (size_t)(kh * 8)  * 256 + k;
            float a0 = 0.f, a1 = 0.f;
#pragma unroll 8
            for (int i = 0; i < 32; ++i) {
                half8 w = wWE[(size_t)i * 256];
                a0 = dot8h(w, *(const half8*)&hc[0 * 512 + kh * 256 + i * 8], a0);
                a1 = dot8h(w, *(const half8*)&hc[1 * 512 + kh * 256 + i * 8], a1);
            }
#pragma unroll
            for (int i = 0; i < 8; ++i) {
                half8 w = wU2[(size_t)i * 256];
                a0 = dot8h(w, *(const half8*)&xhg[0 * 128 + kh * 64 + i * 8], a0);
                a1 = dot8h(w, *(const half8*)&xhg[1 * 128 + kh * 64 + i * 8], a1);
            }
            gbuf[kh * 512 + 0 * 256 + k] = a0;
            gbuf[kh * 512 + 1 * 256 + k] = a1;
        }
        __syncthreads();
        {
            const int b = tid >> 8, k = tid & 255;
            hcxi[b * 256 + k] = gbuf[b * 256 + k] + gbuf[512 + b * 256 + k]
                              + Web[k] + Ue2b[k];
        }
        __syncthreads();

        // (c) scores: thread (b,kh,j); kh=0 from LDS u1, kh=1 from HBM scrA
        {
            const int b = tid >> 8, r = tid & 255, kh = r >> 7, j = r & 127;
            const float* hx = hcxi + b * 256 + kh * 128;
            const float* vw = VeW + kh * 128;
            float acc = kh ? 0.f : Veb[0];
            if (kh == 0) {
                const hf_t* up = u1 + ((size_t)(b * 128)) * 128 + j;
#pragma unroll 8
                for (int k2 = 0; k2 < 128; ++k2) {
                    float u = (float)up[(size_t)k2 * 128];
                    acc = fmaf(vw[k2], tanh_f(hx[k2] + u), acc);
                }
            } else {
                const hf_t* up = scrA + ((size_t)(b0 + b) * 128) * 128 + j;
#pragma unroll 8
                for (int k2 = 0; k2 < 128; ++k2) {
                    float u = (float)nt_load_h(up + (size_t)k2 * 128);
                    acc = fmaf(vw[k2], tanh_f(hx[k2] + u), acc);
                }
            }
            gbuf[(b * 2 + kh) * 128 + j] = acc;   // spart in gbuf[0..512)
        }
        __syncthreads();

        // (d) softmax per b (one wave per b), gate x
        if (tid < 128) {
            const int b = tid >> 6, lane = tid & 63;
            float sA = gbuf[b * 256 + lane]      + gbuf[b * 256 + 128 + lane];
            float sB = gbuf[b * 256 + 64 + lane] + gbuf[b * 256 + 192 + lane];
            float m = fmaxf(sA, sB);
            for (int d = 1; d < 64; d <<= 1) m = fmaxf(m, __shfl_xor(m, d));
            float eA = __expf(sA - m), eB = __expf(sB - m);
            float ssum = eA + eB;
            for (int d = 1; d < 64; d <<= 1) ssum += __shfl_xor(ssum, d);
            float inv = 1.0f / ssum;
            xhg[b * NI_ + lane]      = (hf_t)(xraw[b * NI_ + lane] * eA * inv);
            xhg[b * NI_ + lane + 64] = (hf_t)(xraw[b * NI_ + lane + 64] * eB * inv);
        }
        __syncthreads();

        // (e) encoder gates: thread handles rows o=tid and o+512
        {
            const int o = tid;
            const half8* wih = (const half8*)(wb + W_EWIH) + o;
            const half8* whh = (const half8*)(wb + W_EWHH) + o;
            float bias0 = ebih[o] + ebhh[o];
            float bias1 = ebih[o + 512] + ebhh[o + 512];
            float a00 = bias0, a01 = bias0, a10 = bias1, a11 = bias1;
#pragma unroll 8
            for (int i = 0; i < 16; ++i) {
                half8 w0 = wih[(size_t)i * 1024];
                half8 w1 = wih[(size_t)i * 1024 + 512];
                half8 x0 = *(const half8*)&xhg[0 * 128 + i * 8];
                half8 x1 = *(const half8*)&xhg[1 * 128 + i * 8];
                a00 = dot8h(w0, x0, a00); a01 = dot8h(w0, x1, a01);
                a10 = dot8h(w1, x0, a10); a11 = dot8h(w1, x1, a11);
            }
#pragma unroll 8
            for (int i = 0; i < 32; ++i) {
                half8 w0 = whh[(size_t)i * 1024];
                half8 w1 = whh[(size_t)i * 1024 + 512];
                half8 h0 = *(const half8*)&hc[0 * 512 + i * 8];
                half8 h1 = *(const half8*)&hc[1 * 512 + i * 8];
                a00 = dot8h(w0, h0, a00); a01 = dot8h(w0, h1, a01);
                a10 = dot8h(w1, h0, a10); a11 = dot8h(w1, h1, a11);
            }
            gbuf[o]              = a00; gbuf[1024 + o]       = a01;
            gbuf[o + 512]        = a10; gbuf[1024 + o + 512] = a11;
        }
        __syncthreads();

        // (f) encoder LSTM update (c in register), (b,k) = tid
        {
            const int b = tid >> 8, k = tid & 255;
            float gi = gbuf[b * H4_ + k];
            float gf = gbuf[b * H4_ + H_ + k];
            float gg = gbuf[b * H4_ + 2 * H_ + k];
            float go = gbuf[b * H4_ + 3 * H_ + k];
            float c2 = sigm(gf) * c_enc + sigm(gi) * tanh_f(gg);
            float h2 = sigm(go) * tanh_f(c2);
            c_enc = c2;
            hc[b * 512 + k]       = (hf_t)h2;
            hc[b * 512 + 256 + k] = (hf_t)c2;
        }
        __syncthreads();

        // (g) mid gates: rows o and o+512
        {
            const int o = tid;
            const half8* wih = (const half8*)(wb + W_MWIH) + o;
            const half8* whh = (const half8*)(wb + W_MWHH) + o;
            float bias0 = mbih[o] + mbhh[o];
            float bias1 = mbih[o + 512] + mbhh[o + 512];
            float a00 = bias0, a01 = bias0, a10 = bias1, a11 = bias1;
#pragma unroll 8
            for (int i = 0; i < 32; ++i) {
                half8 w0 = wih[(size_t)i * 1024];
                half8 w1 = wih[(size_t)i * 1024 + 512];
                half8 h0 = *(const half8*)&hc[0 * 512 + i * 8];
                half8 h1 = *(const half8*)&hc[1 * 512 + i * 8];
                a00 = dot8h(w0, h0, a00); a01 = dot8h(w0, h1, a01);
                a10 = dot8h(w1, h0, a10); a11 = dot8h(w1, h1, a11);
            }
#pragma unroll 8
            for (int i = 0; i < 32; ++i) {
                half8 w0 = whh[(size_t)i * 1024];
                half8 w1 = whh[(size_t)i * 1024 + 512];
                half8 m0 = *(const half8*)&hm[0 * 256 + i * 8];
                half8 m1 = *(const half8*)&hm[1 * 256 + i * 8];
                a00 = dot8h(w0, m0, a00); a01 = dot8h(w0, m1, a01);
                a10 = dot8h(w1, m0, a10); a11 = dot8h(w1, m1, a11);
            }
            gbuf[o]              = a00; gbuf[1024 + o]       = a01;
            gbuf[o + 512]        = a10; gbuf[1024 + o + 512] = a11;
        }
        __syncthreads();

        // (h) mid LSTM update + store mid (c in register)
        {
            const int b = tid >> 8, k = tid & 255;
            float gi = gbuf[b * H4_ + k];
            float gf = gbuf[b * H4_ + H_ + k];
            float gg = gbuf[b * H4_ + 2 * H_ + k];
            float go = gbuf[b * H4_ + 3 * H_ + k];
            float c2 = sigm(gf) * c_mid + sigm(gi) * tanh_f(gg);
            float h2 = sigm(go) * tanh_f(c2);
            c_mid = c2;
            hm[b * 256 + k] = (hf_t)h2;
            scrB[((size_t)(b0 + b) * T_ + t) * H_ + k] = (hf_t)h2;
        }
        __syncthreads();
    }

    // ---------- udm pass: o<128 -> LDS u1, o>=128 -> scrA (nt) ----------
    // thread (b, oh, tt): 128 o each; mid rows L1/L2-served.
    {
        const int b = tid >> 8, r = tid & 255, oh = r >> 7, tt = r & 127;
        const half8* mrow = (const half8*)(scrB + ((size_t)(b0 + b) * T_ + tt) * H_);
        const half8* udw = (const half8*)(wb + W_UD);
        for (int o2 = 0; o2 < 128; ++o2) {
            const int o = oh * 128 + o2;
            const half8* ur = udw + (size_t)o * 32;
            float acc = Udb[o];
#pragma unroll 8
            for (int i = 0; i < 32; ++i) acc = dot8h(ur[i], mrow[i], acc);
            if (oh == 0)
                u1[((size_t)(b * 128) + o) * 128 + tt] = (hf_t)acc;
            else
                nt_store_h((hf_t)acc,
                           scrA + (((size_t)(b0 + b) * 128) + o2) * 128 + tt);
        }
    }
    __syncthreads();
    for (int i = tid; i < 512; i += TB) wk[i] = 0.0f;    // zero dec hc
    __syncthreads();

    float c_dec = 0.0f;

    // ---------- Decoder ----------
    for (int s = 0; s < DS_; ++s) {
        // (a') Wd.[h;c] partials, k-HALF split
        {
            const int k = tid & 255, kh = tid >> 8;
            const half8* wWD = (const half8*)(wb + W_WD) + (size_t)(kh * 32) * 256 + k;
            float a0 = 0.f, a1 = 0.f;
#pragma unroll 8
            for (int i = 0; i < 32; ++i) {
                half8 w = wWD[(size_t)i * 256];
                a0 = dot8h(w, *(const half8*)&hc[0 * 512 + kh * 256 + i * 8], a0);
                a1 = dot8h(w, *(const half8*)&hc[1 * 512 + kh * 256 + i * 8], a1);
            }
            gbuf[kh * 512 + 0 * 256 + k] = a0;
            gbuf[kh * 512 + 1 * 256 + k] = a1;
        }
        __syncthreads();
        {
            const int b = tid >> 8, k = tid & 255;
            hcxi[b * 256 + k] = gbuf[b * 256 + k] + gbuf[512 + b * 256 + k] + Wdb[k];
        }
        __syncthreads();

        // (b') temporal scores: thread (b,kh,j); kh=0 LDS u1, kh=1 HBM scrA
        {
            const int b = tid >> 8, r = tid & 255, kh = r >> 7, j = r & 127;
            const float* hx = hcxi + b * 256 + kh * 128;
            const float* vw = VdW + kh * 128;
            float acc = kh ? 0.f : Vdb[0];
            if (kh == 0) {
                const hf_t* up = u1 + ((size_t)(b * 128)) * 128 + j;
#pragma unroll 8
                for (int k2 = 0; k2 < 128; ++k2) {
                    float u = (float)up[(size_t)k2 * 128];
                    acc = fmaf(vw[k2], tanh_f(hx[k2] + u), acc);
                }
            } else {
                const hf_t* up = scrA + ((size_t)(b0 + b) * 128) * 128 + j;
#pragma unroll 8
                for (int k2 = 0; k2 < 128; ++k2) {
                    float u = (float)nt_load_h(up + (size_t)k2 * 128);
                    acc = fmaf(vw[k2], tanh_f(hx[k2] + u), acc);
                }
            }
            gbuf[(b * 2 + kh) * 128 + j] = acc;   // spart [0..512)
        }
        __syncthreads();
        if (tid < 256) {   // sbuf = gbuf[512..768)
            const int b = tid >> 7, j = tid & 127;
            gbuf[512 + b * 128 + j] = gbuf[b * 256 + j] + gbuf[b * 256 + 128 + j];
        }
        __syncthreads();

        // (d') dec_in[b,h] = sum_j t[b,j] * mid[b,j,h]; (b,h) = tid
        {
            const int b = tid >> 8, h = tid & 255;
            const hf_t* mp = scrB + (size_t)(b0 + b) * T_ * H_ + h;
            const float* sb = gbuf + 512 + b * 128;
            float acc = 0.0f;
            for (int j = 0; j < T_; ++j)
                acc = fmaf(sb[j], (float)mp[(size_t)j * H_], acc);
            dinh[b * 256 + h] = (hf_t)acc;
        }
        __syncthreads();

        // (e') decoder gates: rows o and o+512
        {
            const int o = tid;
            const half8* wih = (const half8*)(wb + W_DWIH) + o;
            const half8* whh = (const half8*)(wb + W_DWHH) + o;
            float bias0 = dbih[o] + dbhh[o];
            float bias1 = dbih[o + 512] + dbhh[o + 512];
            float a00 = bias0, a01 = bias0, a10 = bias1, a11 = bias1;
#pragma unroll 8
            for (int i = 0; i < 32; ++i) {
                half8 w0 = wih[(size_t)i * 1024];
                half8 w1 = wih[(size_t)i * 1024 + 512];
                half8 d0 = *(const half8*)&dinh[0 * 256 + i * 8];
                half8 d1 = *(const half8*)&dinh[1 * 256 + i * 8];
                a00 = dot8h(w0, d0, a00); a01 = dot8h(w0, d1, a01);
                a10 = dot8h(w1, d0, a10); a11 = dot8h(w1, d1, a11);
            }
#pragma unroll 8
            for (int i = 0; i < 32; ++i) {
                half8 w0 = whh[(size_t)i * 1024];
                half8 w1 = whh[(size_t)i * 1024 + 512];
                half8 h0 = *(const half8*)&hc[0 * 512 + i * 8];
                half8 h1 = *(const half8*)&hc[1 * 512 + i * 8];
                a00 = dot8h(w0, h0, a00); a01 = dot8h(w0, h1, a01);
                a10 = dot8h(w1, h0, a10); a11 = dot8h(w1, h1, a11);
            }
            gbuf[o]              = a00; gbuf[1024 + o]       = a01;
            gbuf[o + 512]        = a10; gbuf[1024 + o + 512] = a11;
        }
        __syncthreads();

        // (f') decoder LSTM update (c in register), keep h2 for (g')
        float h2dec;
        {
            const int b = tid >> 8, k = tid & 255;
            float gi = gbuf[b * H4_ + k];
            float gf = gbuf[b * H4_ + H_ + k];
            float gg = gbuf[b * H4_ + 2 * H_ + k];
            float go = gbuf[b * H4_ + 3 * H_ + k];
            float c2 = sigm(gf) * c_dec + sigm(gi) * tanh_f(gg);
            h2dec = sigm(go) * tanh_f(c2);
            c_dec = c2;
            hc[b * 512 + k]       = (hf_t)h2dec;
            hc[b * 512 + 256 + k] = (hf_t)c2;
        }
        __syncthreads();

        // (g') out[b, s-6] = rW.h + rb  (wave shuffle reduce)
        if (s >= 6) {
            const int k = tid & 255;
            float p = rW[k] * h2dec;
            for (int d = 1; d < 64; d <<= 1) p += __shfl_xor(p, d);
            if ((tid & 63) == 0) red[tid >> 6] = p;   // red[w], w = 0..7
        }
        __syncthreads();
        if (s >= 6 && tid < 2) {
            float v = red[tid * 4] + red[tid * 4 + 1]
                    + red[tid * 4 + 2] + red[tid * 4 + 3] + rb[0];
            out[(size_t)(b0 + tid) * TD_ + (s - 6)] = v;
        }
        __syncthreads();
    }
}

extern "C" void kernel_launch(void* const* d_in, const int* in_sizes, int n_in,
                              void* d_out, int out_size, void* d_ws, size_t ws_size,
                              hipStream_t stream) {
    const float* inp  = (const float*)d_in[0];
    const float* UeW  = (const float*)d_in[2];
    const float* Ueb  = (const float*)d_in[3];
    const float* Ue2W = (const float*)d_in[4];
    const float* Ue2b = (const float*)d_in[5];
    const float* WeW  = (const float*)d_in[6];
    const float* Web  = (const float*)d_in[7];
    const float* VeW  = (const float*)d_in[8];
    const float* Veb  = (const float*)d_in[9];
    const float* UdW  = (const float*)d_in[10];
    const float* Udb  = (const float*)d_in[11];
    const float* WdW  = (const float*)d_in[12];
    const float* Wdb  = (const float*)d_in[13];
    const float* VdW  = (const float*)d_in[14];
    const float* Vdb  = (const float*)d_in[15];
    const float* eWih = (const float*)d_in[16];
    const float* eWhh = (const float*)d_in[17];
    const float* ebih = (const float*)d_in[18];
    const float* ebhh = (const float*)d_in[19];
    const float* mWih = (const float*)d_in[20];
    const float* mWhh = (const float*)d_in[21];
    const float* mbih = (const float*)d_in[22];
    const float* mbhh = (const float*)d_in[23];
    const float* dWih = (const float*)d_in[24];
    const float* dWhh = (const float*)d_in[25];
    const float* dbih = (const float*)d_in[26];
    const float* dbhh = (const float*)d_in[27];
    const float* rW   = (const float*)d_in[28];
    const float* rb   = (const float*)d_in[29];

    hf_t* wsb  = (hf_t*)d_ws;
    hf_t* scrA = wsb + SCR_A;
    hf_t* scrB = wsb + SCR_B;

    // allow 80 KB dynamic LDS (one-time attribute; host-side, graph-safe)
    static bool attr_set = false;
    if (!attr_set) {
        hipFuncSetAttribute((const void*)dsrnn_kernel,
                            hipFuncAttributeMaxDynamicSharedMemorySize, LDS_BYTES);
        attr_set = true;
    }

    convw_kernel<<<512, 256, 0, stream>>>(WeW, Ue2W, eWih, eWhh, mWih, mWhh,
                                          dWih, dWhh, WdW, UdW, wsb);

    dsrnn_kernel<<<B_ / BB, TB, LDS_BYTES, stream>>>(
        inp, UeW, Ueb, Ue2b, Web, VeW, Veb, Udb, Wdb, VdW, Vdb,
        ebih, ebhh, mbih, mbhh, dbih, dbhh, rW, rb,
        wsb, scrA, scrB, (float*)d_out);
}

// Round 13
// 10332.064 us; speedup vs baseline: 1.6981x; 1.6981x over previous
//
#include <hip/hip_runtime.h>

// DA-RNN persistent kernel, round 14: R9 (best, 10.31 ms) + latency trims.
// R12 closed the occupancy book: grid must stay 256 (weight amortization);
// 1 block/CU, 16 waves is structural. R9 profile: VALU 44%, HBM 6.6% ->
// ~5.8 ms is intra-phase memory latency + ~1400 barrier drains. This round:
//  1. fold phase (a) into (h): load x_{t+1} in (h) (x dead there); x_0
//     preloaded in zero phase. -128 barriers.
//  2. unroll 16 on HBM score loops ((c)/(b') kh=1): 2x loads in flight.
//  3. unroll 16 on (d') mid-row loop.
// No thread-map/LDS changes; math identical to R9 (passed, absmax 9.77e-4).

#define B_   1024
#define T_   128     // T_ENCO
#define NI_  128     // N_INP
#define H_   256     // N_HID
#define H4_  1024    // 4*N_HID
#define TD_  24      // T_DECO
#define DS_  30      // decoder steps
#define BB   4       // batch rows per workgroup
#define TB   1024    // threads per block
#define LDS_BYTES 163840u   // 32 KB wk + 128 KB u1

typedef _Float16 hf_t;
typedef _Float16 half8  __attribute__((ext_vector_type(8)));
typedef _Float16 half2v __attribute__((ext_vector_type(2)));

__device__ __forceinline__ float sigm(float x) {
    return __builtin_amdgcn_rcpf(1.0f + __expf(-x));
}
__device__ __forceinline__ float tanh_f(float x) {
    float e = __expf(2.0f * x);
    return 1.0f - 2.0f * __builtin_amdgcn_rcpf(e + 1.0f);
}
__device__ __forceinline__ float fdot2f(half2v a, half2v b, float c) {
#if __has_builtin(__builtin_amdgcn_fdot2)
    return __builtin_amdgcn_fdot2(a, b, c, false);
#else
    return fmaf((float)a.x, (float)b.x, fmaf((float)a.y, (float)b.y, c));
#endif
}
__device__ __forceinline__ float dot8h(half8 w, half8 x, float acc) {
    acc = fdot2f(__builtin_shufflevector(w, w, 0, 1), __builtin_shufflevector(x, x, 0, 1), acc);
    acc = fdot2f(__builtin_shufflevector(w, w, 2, 3), __builtin_shufflevector(x, x, 2, 3), acc);
    acc = fdot2f(__builtin_shufflevector(w, w, 4, 5), __builtin_shufflevector(x, x, 4, 5), acc);
    acc = fdot2f(__builtin_shufflevector(w, w, 6, 7), __builtin_shufflevector(x, x, 6, 7), acc);
    return acc;
}
__device__ __forceinline__ hf_t nt_load_h(const hf_t* p) {
#if __has_builtin(__builtin_nontemporal_load)
    return __builtin_nontemporal_load(p);
#else
    return *p;
#endif
}
__device__ __forceinline__ void nt_store_h(hf_t v, hf_t* p) {
#if __has_builtin(__builtin_nontemporal_store)
    __builtin_nontemporal_store(v, p);
#else
    *p = v;
#endif
}

// ---- f16 weight layout inside d_ws (offsets in halves) ----
#define W_WE    0u
#define W_UE2   131072u
#define W_EWIH  163840u
#define W_EWHH  294912u
#define W_MWIH  557056u
#define W_MWHH  819200u
#define W_DWIH  1081344u
#define W_DWHH  1343488u
#define W_WD    1605632u
#define W_UD    1736704u
#define SCR_A   2097152u       // upper halves: uexT k>=128 -> udmT o>=128 [b][0..127][j]
#define SCR_B   35651584u      // midb [b][t][k]

__global__ void convw_kernel(const float* __restrict__ sWE, const float* __restrict__ sUE2,
                             const float* __restrict__ sEI, const float* __restrict__ sEH,
                             const float* __restrict__ sMI, const float* __restrict__ sMH,
                             const float* __restrict__ sDI, const float* __restrict__ sDH,
                             const float* __restrict__ sWD, const float* __restrict__ sUD,
                             hf_t* __restrict__ dst) {
    const int gtid = blockIdx.x * blockDim.x + threadIdx.x;
    const int gs   = gridDim.x * blockDim.x;
    for (int n = gtid; n < 131072; n += gs) {       // WE'
        int e = n & 7, q = n >> 3, k = q & 255, c = q >> 8, kq = c >> 4, i = c & 15;
        dst[W_WE + n] = (hf_t)sWE[k * 512 + kq * 128 + i * 8 + e];
    }
    for (int n = gtid; n < 32768; n += gs) {        // UE2'
        int e = n & 7, q = n >> 3, k = q & 255, c = q >> 8, kq = c >> 2, i = c & 3;
        dst[W_UE2 + n] = (hf_t)sUE2[k * 128 + kq * 32 + i * 8 + e];
    }
    for (int n = gtid; n < 131072; n += gs) {       // EWIH' (K=128)
        int e = n & 7, q = n >> 3, o = q & 1023, i = q >> 10;
        dst[W_EWIH + n] = (hf_t)sEI[o * 128 + i * 8 + e];
    }
    for (int n = gtid; n < 262144; n += gs) {       // K=256 gates
        int e = n & 7, q = n >> 3, o = q & 1023, i = q >> 10;
        int s = o * 256 + i * 8 + e;
        dst[W_EWHH + n] = (hf_t)sEH[s];
        dst[W_MWIH + n] = (hf_t)sMI[s];
        dst[W_MWHH + n] = (hf_t)sMH[s];
        dst[W_DWIH + n] = (hf_t)sDI[s];
        dst[W_DWHH + n] = (hf_t)sDH[s];
    }
    for (int n = gtid; n < 131072; n += gs) {       // WD'
        int e = n & 7, q = n >> 3, k = q & 255, c = q >> 8, kq = c >> 4, i = c & 15;
        dst[W_WD + n] = (hf_t)sWD[k * 512 + kq * 128 + i * 8 + e];
    }
    for (int n = gtid; n < 65536; n += gs)          // UD plain
        dst[W_UD + n] = (hf_t)sUD[n];
}

// ---- wk offsets (floats, wk = sm[0..8192)) ----
#define O_HC    0        // hf [4][512]                      1024f
#define O_HM    1024     // hf [4][256] (decoder: dinh)       512f
#define O_XRAW  1536     // f32 [4][128]                      512f
#define O_XHG   2048     // hf [4][128]  xh then xg           256f
#define O_HCXI  2304     // f32 [4][256]                     1024f
#define O_VES   3328     // f32 [256]
#define O_VDS   3584     // f32 [256]
#define O_RED   3840     // f32 [16] output-reduce partials
#define O_GBUF  4096     // f32 [4096] gates / partials / scores / sbuf
// phase-0 X staging reuses wk[0..8192) as f32[128][64]

__global__ __launch_bounds__(TB, 4) void dsrnn_kernel(
    const float* __restrict__ inp,
    const float* __restrict__ UeW,  const float* __restrict__ Ueb,
    const float* __restrict__ Ue2b,
    const float* __restrict__ Web,
    const float* __restrict__ VeW,  const float* __restrict__ Veb,
    const float* __restrict__ Udb,
    const float* __restrict__ Wdb,
    const float* __restrict__ VdW,  const float* __restrict__ Vdb,
    const float* __restrict__ ebih, const float* __restrict__ ebhh,
    const float* __restrict__ mbih, const float* __restrict__ mbhh,
    const float* __restrict__ dbih, const float* __restrict__ dbhh,
    const float* __restrict__ rW,   const float* __restrict__ rb,
    const hf_t* __restrict__ wb,
    hf_t* __restrict__ scrA,
    hf_t* __restrict__ scrB,
    float* __restrict__ out)
{
    extern __shared__ float sm[];
    float* wk = sm;                       // 8192 floats = 32 KB
    hf_t*  u1 = (hf_t*)(sm + 8192);       // 65536 halves = 128 KB

    const int tid = threadIdx.x;
    const int b0  = blockIdx.x * BB;

    hf_t*  hc   = (hf_t*)(wk + O_HC);
    hf_t*  hm   = (hf_t*)(wk + O_HM);
    float* xraw = wk + O_XRAW;
    hf_t*  xhg  = (hf_t*)(wk + O_XHG);
    float* hcxi = wk + O_HCXI;
    float* ves  = wk + O_VES;
    float* vds  = wk + O_VDS;
    float* red  = wk + O_RED;
    float* gbuf = wk + O_GBUF;
    hf_t*  dinh = (hf_t*)(wk + O_HM);     // decoder alias of HM

    // ---------- Phase 0: uexT; k<128 -> LDS u1, k>=128 -> scrA (nt) ----------
    {
        const int jj = tid & 63;        // j within half
        const int kg = tid >> 6;        // 16 groups x 16 k
        for (int b = 0; b < BB; ++b) {
            const float* Xg = inp + (size_t)(b0 + b) * T_ * NI_;
            for (int jh = 0; jh < 2; ++jh) {
                __syncthreads();
                for (int i = tid; i < 128 * 64; i += TB) {
                    int t = i >> 6, j2 = i & 63;
                    wk[i] = Xg[t * NI_ + jh * 64 + j2];
                }
                __syncthreads();
                const int j = jh * 64 + jj;
                for (int k = kg * 16; k < kg * 16 + 16; ++k) {
                    const float* wrow = UeW + (size_t)k * T_;
                    float acc = Ueb[k];
#pragma unroll 4
                    for (int t = 0; t < T_; ++t) acc = fmaf(wrow[t], wk[t * 64 + jj], acc);
                    if (k < 128)
                        u1[((size_t)(b * 128) + k) * 128 + j] = (hf_t)acc;
                    else
                        nt_store_h((hf_t)acc,
                                   scrA + (((size_t)(b0 + b) * 128) + (k - 128)) * 128 + j);
                }
            }
        }
    }
    __syncthreads();
    for (int i = tid; i < 1536; i += TB) wk[i] = 0.0f;   // zero hc + hm
    if (tid < 256) { ves[tid] = VeW[tid]; vds[tid] = VdW[tid]; }
    if (tid < 512) {   // preload x_0 (phase (a) folded away)
        const int b = tid >> 7, j = tid & 127;
        float v = inp[((size_t)(b0 + b) * T_) * NI_ + j];
        xraw[b * NI_ + j] = v;
        xhg[b * NI_ + j]  = (hf_t)v;
    }
    __syncthreads();

    float c_enc = 0.0f, c_mid = 0.0f;   // f32 c-states in registers, (b,k)=tid

    // ---------- Fused encoder + mid loop (x_t preloaded by prev (h)) ----------
    for (int t = 0; t < T_; ++t) {
        // (b) We.[h;c] + Ue2.x partials, k-quarter split
        {
            const int k = tid & 255, kq = tid >> 8;
            const half8* wWE = (const half8*)(wb + W_WE)  + (size_t)(kq * 16) * 256 + k;
            const half8* wU2 = (const half8*)(wb + W_UE2) + (size_t)(kq * 4)  * 256 + k;
            float a0 = 0.f, a1 = 0.f, a2 = 0.f, a3 = 0.f;
#pragma unroll 8
            for (int i = 0; i < 16; ++i) {
                half8 w = wWE[(size_t)i * 256];
                a0 = dot8h(w, *(const half8*)&hc[0 * 512 + kq * 128 + i * 8], a0);
                a1 = dot8h(w, *(const half8*)&hc[1 * 512 + kq * 128 + i * 8], a1);
                a2 = dot8h(w, *(const half8*)&hc[2 * 512 + kq * 128 + i * 8], a2);
                a3 = dot8h(w, *(const half8*)&hc[3 * 512 + kq * 128 + i * 8], a3);
            }
#pragma unroll
            for (int i = 0; i < 4; ++i) {
                half8 w = wU2[(size_t)i * 256];
                a0 = dot8h(w, *(const half8*)&xhg[0 * 128 + kq * 32 + i * 8], a0);
                a1 = dot8h(w, *(const half8*)&xhg[1 * 128 + kq * 32 + i * 8], a1);
                a2 = dot8h(w, *(const half8*)&xhg[2 * 128 + kq * 32 + i * 8], a2);
                a3 = dot8h(w, *(const half8*)&xhg[3 * 128 + kq * 32 + i * 8], a3);
            }
            gbuf[kq * 1024 + 0 * 256 + k] = a0;
            gbuf[kq * 1024 + 1 * 256 + k] = a1;
            gbuf[kq * 1024 + 2 * 256 + k] = a2;
            gbuf[kq * 1024 + 3 * 256 + k] = a3;
        }
        __syncthreads();
        {
            const int b = tid >> 8, k = tid & 255;
            hcxi[b * 256 + k] = gbuf[b * 256 + k] + gbuf[1024 + b * 256 + k]
                              + gbuf[2048 + b * 256 + k] + gbuf[3072 + b * 256 + k]
                              + Web[k] + Ue2b[k];
        }
        __syncthreads();

        // (c) scores: kh=0 from LDS u1, kh=1 from HBM scrA (nt, unroll 16)
        {
            const int b = tid >> 8, r = tid & 255, kh = r >> 7, j = r & 127;
            const float* hx = hcxi + b * 256 + kh * 128;
            const float* vw = ves + kh * 128;
            float acc = kh ? 0.f : Veb[0];
            if (kh == 0) {
                const hf_t* up = u1 + ((size_t)(b * 128)) * 128 + j;
#pragma unroll 8
                for (int k2 = 0; k2 < 128; ++k2) {
                    float u = (float)up[(size_t)k2 * 128];
                    acc = fmaf(vw[k2], tanh_f(hx[k2] + u), acc);
                }
            } else {
                const hf_t* up = scrA + ((size_t)(b0 + b) * 128) * 128 + j;
#pragma unroll 16
                for (int k2 = 0; k2 < 128; ++k2) {
                    float u = (float)nt_load_h(up + (size_t)k2 * 128);
                    acc = fmaf(vw[k2], tanh_f(hx[k2] + u), acc);
                }
            }
            gbuf[tid] = acc;   // score partials in gbuf[0..1024)
        }
        __syncthreads();

        // (d) softmax per b (one wave per b), gate x
        if (tid < 256) {
            const int b = tid >> 6, lane = tid & 63;
            const int base = b << 8;
            float sA = gbuf[base + lane]      + gbuf[base + 128 + lane];
            float sB = gbuf[base + 64 + lane] + gbuf[base + 192 + lane];
            float m = fmaxf(sA, sB);
            for (int d = 1; d < 64; d <<= 1) m = fmaxf(m, __shfl_xor(m, d));
            float eA = __expf(sA - m), eB = __expf(sB - m);
            float ssum = eA + eB;
            for (int d = 1; d < 64; d <<= 1) ssum += __shfl_xor(ssum, d);
            float inv = 1.0f / ssum;
            xhg[b * NI_ + lane]      = (hf_t)(xraw[b * NI_ + lane] * eA * inv);
            xhg[b * NI_ + lane + 64] = (hf_t)(xraw[b * NI_ + lane + 64] * eB * inv);
        }
        __syncthreads();

        // (e) encoder gates: thread o owns row o (read exactly once)
        {
            const int o = tid;
            const half8* wih = (const half8*)(wb + W_EWIH) + o;
            const half8* whh = (const half8*)(wb + W_EWHH) + o;
            float bias = ebih[o] + ebhh[o];
            float a0 = bias, a1 = bias, a2 = bias, a3 = bias;
#pragma unroll 8
            for (int i = 0; i < 16; ++i) {
                half8 w = wih[(size_t)i * 1024];
                a0 = dot8h(w, *(const half8*)&xhg[0 * 128 + i * 8], a0);
                a1 = dot8h(w, *(const half8*)&xhg[1 * 128 + i * 8], a1);
                a2 = dot8h(w, *(const half8*)&xhg[2 * 128 + i * 8], a2);
                a3 = dot8h(w, *(const half8*)&xhg[3 * 128 + i * 8], a3);
            }
#pragma unroll 8
            for (int i = 0; i < 32; ++i) {
                half8 w = whh[(size_t)i * 1024];
                a0 = dot8h(w, *(const half8*)&hc[0 * 512 + i * 8], a0);
                a1 = dot8h(w, *(const half8*)&hc[1 * 512 + i * 8], a1);
                a2 = dot8h(w, *(const half8*)&hc[2 * 512 + i * 8], a2);
                a3 = dot8h(w, *(const half8*)&hc[3 * 512 + i * 8], a3);
            }
            gbuf[0 * 1024 + o] = a0; gbuf[1 * 1024 + o] = a1;
            gbuf[2 * 1024 + o] = a2; gbuf[3 * 1024 + o] = a3;
        }
        __syncthreads();

        // (f) encoder LSTM update (c in register)
        {
            const int b = tid >> 8, k = tid & 255;
            float gi = gbuf[b * H4_ + k];
            float gf = gbuf[b * H4_ + H_ + k];
            float gg = gbuf[b * H4_ + 2 * H_ + k];
            float go = gbuf[b * H4_ + 3 * H_ + k];
            float c2 = sigm(gf) * c_enc + sigm(gi) * tanh_f(gg);
            float h2 = sigm(go) * tanh_f(c2);
            c_enc = c2;
            hc[b * 512 + k]       = (hf_t)h2;
            hc[b * 512 + 256 + k] = (hf_t)c2;
        }
        __syncthreads();

        // (g) mid gates
        {
            const int o = tid;
            const half8* wih = (const half8*)(wb + W_MWIH) + o;
            const half8* whh = (const half8*)(wb + W_MWHH) + o;
            float bias = mbih[o] + mbhh[o];
            float a0 = bias, a1 = bias, a2 = bias, a3 = bias;
#pragma unroll 8
            for (int i = 0; i < 32; ++i) {
                half8 w = wih[(size_t)i * 1024];
                a0 = dot8h(w, *(const half8*)&hc[0 * 512 + i * 8], a0);
                a1 = dot8h(w, *(const half8*)&hc[1 * 512 + i * 8], a1);
                a2 = dot8h(w, *(const half8*)&hc[2 * 512 + i * 8], a2);
                a3 = dot8h(w, *(const half8*)&hc[3 * 512 + i * 8], a3);
            }
#pragma unroll 8
            for (int i = 0; i < 32; ++i) {
                half8 w = whh[(size_t)i * 1024];
                a0 = dot8h(w, *(const half8*)&hm[0 * 256 + i * 8], a0);
                a1 = dot8h(w, *(const half8*)&hm[1 * 256 + i * 8], a1);
                a2 = dot8h(w, *(const half8*)&hm[2 * 256 + i * 8], a2);
                a3 = dot8h(w, *(const half8*)&hm[3 * 256 + i * 8], a3);
            }
            gbuf[0 * 1024 + o] = a0; gbuf[1 * 1024 + o] = a1;
            gbuf[2 * 1024 + o] = a2; gbuf[3 * 1024 + o] = a3;
        }
        __syncthreads();

        // (h) mid LSTM update + store mid + preload x_{t+1} (phase (a) folded)
        {
            const int b = tid >> 8, k = tid & 255;
            float gi = gbuf[b * H4_ + k];
            float gf = gbuf[b * H4_ + H_ + k];
            float gg = gbuf[b * H4_ + 2 * H_ + k];
            float go = gbuf[b * H4_ + 3 * H_ + k];
            float c2 = sigm(gf) * c_mid + sigm(gi) * tanh_f(gg);
            float h2 = sigm(go) * tanh_f(c2);
            c_mid = c2;
            hm[b * 256 + k] = (hf_t)h2;
            scrB[((size_t)(b0 + b) * T_ + t) * H_ + k] = (hf_t)h2;
        }
        if (t + 1 < T_ && tid < 512) {
            const int b2 = tid >> 7, j2 = tid & 127;
            float v = inp[((size_t)(b0 + b2) * T_ + (t + 1)) * NI_ + j2];
            xraw[b2 * NI_ + j2] = v;
            xhg[b2 * NI_ + j2]  = (hf_t)v;
        }
        __syncthreads();
    }

    // ---------- udm pass: o<128 -> LDS u1, o>=128 -> scrA (nt) ----------
    {
        const int b = tid >> 8, r = tid & 255, oh = r >> 7, tt = r & 127;
        const half8* mrow = (const half8*)(scrB + ((size_t)(b0 + b) * T_ + tt) * H_);
        const half8* udw = (const half8*)(wb + W_UD);
        for (int o2 = 0; o2 < 128; ++o2) {
            const int o = oh * 128 + o2;
            const half8* ur = udw + (size_t)o * 32;
            float acc = Udb[o];
#pragma unroll 8
            for (int i = 0; i < 32; ++i) acc = dot8h(ur[i], mrow[i], acc);
            if (oh == 0)
                u1[((size_t)(b * 128) + o) * 128 + tt] = (hf_t)acc;
            else
                nt_store_h((hf_t)acc,
                           scrA + (((size_t)(b0 + b) * 128) + o2) * 128 + tt);
        }
    }
    __syncthreads();
    for (int i = tid; i < 1024; i += TB) wk[i] = 0.0f;   // zero dec hc
    __syncthreads();

    float c_dec = 0.0f;

    // ---------- Decoder ----------
    for (int s = 0; s < DS_; ++s) {
        // (a') Wd.[h;c] partials, k-quarter split
        {
            const int k = tid & 255, kq = tid >> 8;
            const half8* wWD = (const half8*)(wb + W_WD) + (size_t)(kq * 16) * 256 + k;
            float a0 = 0.f, a1 = 0.f, a2 = 0.f, a3 = 0.f;
#pragma unroll 8
            for (int i = 0; i < 16; ++i) {
                half8 w = wWD[(size_t)i * 256];
                a0 = dot8h(w, *(const half8*)&hc[0 * 512 + kq * 128 + i * 8], a0);
                a1 = dot8h(w, *(const half8*)&hc[1 * 512 + kq * 128 + i * 8], a1);
                a2 = dot8h(w, *(const half8*)&hc[2 * 512 + kq * 128 + i * 8], a2);
                a3 = dot8h(w, *(const half8*)&hc[3 * 512 + kq * 128 + i * 8], a3);
            }
            gbuf[kq * 1024 + 0 * 256 + k] = a0;
            gbuf[kq * 1024 + 1 * 256 + k] = a1;
            gbuf[kq * 1024 + 2 * 256 + k] = a2;
            gbuf[kq * 1024 + 3 * 256 + k] = a3;
        }
        __syncthreads();
        {
            const int b = tid >> 8, k = tid & 255;
            hcxi[b * 256 + k] = gbuf[b * 256 + k] + gbuf[1024 + b * 256 + k]
                              + gbuf[2048 + b * 256 + k] + gbuf[3072 + b * 256 + k]
                              + Wdb[k];
        }
        __syncthreads();

        // (b') temporal scores: kh=0 LDS u1, kh=1 HBM scrA (nt, unroll 16)
        {
            const int b = tid >> 8, r = tid & 255, kh = r >> 7, j = r & 127;
            const float* hx = hcxi + b * 256 + kh * 128;
            const float* vw = vds + kh * 128;
            float acc = kh ? 0.f : Vdb[0];
            if (kh == 0) {
                const hf_t* up = u1 + ((size_t)(b * 128)) * 128 + j;
#pragma unroll 8
                for (int k2 = 0; k2 < 128; ++k2) {
                    float u = (float)up[(size_t)k2 * 128];
                    acc = fmaf(vw[k2], tanh_f(hx[k2] + u), acc);
                }
            } else {
                const hf_t* up = scrA + ((size_t)(b0 + b) * 128) * 128 + j;
#pragma unroll 16
                for (int k2 = 0; k2 < 128; ++k2) {
                    float u = (float)nt_load_h(up + (size_t)k2 * 128);
                    acc = fmaf(vw[k2], tanh_f(hx[k2] + u), acc);
                }
            }
            gbuf[tid] = acc;
        }
        __syncthreads();
        if (tid < 512) {   // sbuf = gbuf[1024..1536)
            const int b = tid >> 7, j = tid & 127;
            gbuf[1024 + b * 128 + j] = gbuf[(b << 8) + j] + gbuf[(b << 8) + 128 + j];
        }
        __syncthreads();

        // (d') dec_in[b,h] = sum_j t[b,j] * mid[b,j,h] (unroll 16)
        {
            const int b = tid >> 8, h = tid & 255;
            const hf_t* mp = scrB + (size_t)(b0 + b) * T_ * H_ + h;
            const float* sb = gbuf + 1024 + b * 128;
            float acc = 0.0f;
#pragma unroll 16
            for (int j = 0; j < T_; ++j)
                acc = fmaf(sb[j], (float)mp[(size_t)j * H_], acc);
            dinh[b * 256 + h] = (hf_t)acc;
        }
        __syncthreads();

        // (e') decoder gates
        {
            const int o = tid;
            const half8* wih = (const half8*)(wb + W_DWIH) + o;
            const half8* whh = (const half8*)(wb + W_DWHH) + o;
            float bias = dbih[o] + dbhh[o];
            float a0 = bias, a1 = bias, a2 = bias, a3 = bias;
#pragma unroll 8
            for (int i = 0; i < 32; ++i) {
                half8 w = wih[(size_t)i * 1024];
                a0 = dot8h(w, *(const half8*)&dinh[0 * 256 + i * 8], a0);
                a1 = dot8h(w, *(const half8*)&dinh[1 * 256 + i * 8], a1);
                a2 = dot8h(w, *(const half8*)&dinh[2 * 256 + i * 8], a2);
                a3 = dot8h(w, *(const half8*)&dinh[3 * 256 + i * 8], a3);
            }
#pragma unroll 8
            for (int i = 0; i < 32; ++i) {
                half8 w = whh[(size_t)i * 1024];
                a0 = dot8h(w, *(const half8*)&hc[0 * 512 + i * 8], a0);
                a1 = dot8h(w, *(const half8*)&hc[1 * 512 + i * 8], a1);
                a2 = dot8h(w, *(const half8*)&hc[2 * 512 + i * 8], a2);
                a3 = dot8h(w, *(const half8*)&hc[3 * 512 + i * 8], a3);
            }
            gbuf[0 * 1024 + o] = a0; gbuf[1 * 1024 + o] = a1;
            gbuf[2 * 1024 + o] = a2; gbuf[3 * 1024 + o] = a3;
        }
        __syncthreads();

        // (f') decoder LSTM update (c in register), keep h2 for (g')
        float h2dec;
        {
            const int b = tid >> 8, k = tid & 255;
            float gi = gbuf[b * H4_ + k];
            float gf = gbuf[b * H4_ + H_ + k];
            float gg = gbuf[b * H4_ + 2 * H_ + k];
            float go = gbuf[b * H4_ + 3 * H_ + k];
            float c2 = sigm(gf) * c_dec + sigm(gi) * tanh_f(gg);
            h2dec = sigm(go) * tanh_f(c2);
            c_dec = c2;
            hc[b * 512 + k]       = (hf_t)h2dec;
            hc[b * 512 + 256 + k] = (hf_t)c2;
        }
        __syncthreads();

        // (g') out[b, s-6] = rW.h + rb  (wave shuffle reduce)
        if (s >= 6) {
            const int k = tid & 255;
            float p = rW[k] * h2dec;
            for (int d = 1; d < 64; d <<= 1) p += __shfl_xor(p, d);
            if ((tid & 63) == 0) red[tid >> 6] = p;   // red[w], w = 0..15
        }
        __syncthreads();
        if (s >= 6 && tid < 4) {
            float v = red[tid * 4] + red[tid * 4 + 1]
                    + red[tid * 4 + 2] + red[tid * 4 + 3] + rb[0];
            out[(size_t)(b0 + tid) * TD_ + (s - 6)] = v;
        }
        __syncthreads();
    }
}

extern "C" void kernel_launch(void* const* d_in, const int* in_sizes, int n_in,
                              void* d_out, int out_size, void* d_ws, size_t ws_size,
                              hipStream_t stream) {
    const float* inp  = (const float*)d_in[0];
    const float* UeW  = (const float*)d_in[2];
    const float* Ueb  = (const float*)d_in[3];
    const float* Ue2W = (const float*)d_in[4];
    const float* Ue2b = (const float*)d_in[5];
    const float* WeW  = (const float*)d_in[6];
    const float* Web  = (const float*)d_in[7];
    const float* VeW  = (const float*)d_in[8];
    const float* Veb  = (const float*)d_in[9];
    const float* UdW  = (const float*)d_in[10];
    const float* Udb  = (const float*)d_in[11];
    const float* WdW  = (const float*)d_in[12];
    const float* Wdb  = (const float*)d_in[13];
    const float* VdW  = (const float*)d_in[14];
    const float* Vdb  = (const float*)d_in[15];
    const float* eWih = (const float*)d_in[16];
    const float* eWhh = (const float*)d_in[17];
    const float* ebih = (const float*)d_in[18];
    const float* ebhh = (const float*)d_in[19];
    const float* mWih = (const float*)d_in[20];
    const float* mWhh = (const float*)d_in[21];
    const float* mbih = (const float*)d_in[22];
    const float* mbhh = (const float*)d_in[23];
    const float* dWih = (const float*)d_in[24];
    const float* dWhh = (const float*)d_in[25];
    const float* dbih = (const float*)d_in[26];
    const float* dbhh = (const float*)d_in[27];
    const float* rW   = (const float*)d_in[28];
    const float* rb   = (const float*)d_in[29];

    hf_t* wsb  = (hf_t*)d_ws;
    hf_t* scrA = wsb + SCR_A;
    hf_t* scrB = wsb + SCR_B;

    // allow 160 KB dynamic LDS (one-time attribute; host-side, graph-safe)
    static bool attr_set = false;
    if (!attr_set) {
        hipFuncSetAttribute((const void*)dsrnn_kernel,
                            hipFuncAttributeMaxDynamicSharedMemorySize, LDS_BYTES);
        attr_set = true;
    }

    convw_kernel<<<512, 256, 0, stream>>>(WeW, Ue2W, eWih, eWhh, mWih, mWhh,
                                          dWih, dWhh, WdW, UdW, wsb);

    dsrnn_kernel<<<B_ / BB, TB, LDS_BYTES, stream>>>(
        inp, UeW, Ueb, Ue2b, Web, VeW, Veb, Udb, Wdb, VdW, Vdb,
        ebih, ebhh, mbih, mbhh, dbih, dbhh, rW, rb,
        wsb, scrA, scrB, (float*)d_out);
}